// Round 1
// 336.375 us; speedup vs baseline: 1.0172x; 1.0172x over previous
//
#include <hip/hip_runtime.h>
#include <math.h>

#define B 16
#define N 2000
#define D 25088            // 512*7*7
#define D4 6272            // D/4
#define PI2 1.570795f      // 3.14159/2, matches the torch-module constant
#define KC 28              // K-chunks in k_dots (7 block-y x 4 waves)
#define KSPAN (D / KC)     // 896
#define KTILES (KSPAN / 32)// 28 MFMA k-steps per wave
#define NT (D / 32)        // 784 k-tiles total
#define NCHUNK 20          // R0: 25->20 -> grid (25,20)=500 blocks, single round
#define NPER (N / NCHUNK)  // 100
#define SELHI 0x07060302u  // v_perm selector: pack hi16(x0)|hi16(x1)<<16

typedef __attribute__((ext_vector_type(8))) short short8;   // 8 x bf16 frag
typedef __attribute__((ext_vector_type(4))) float f32x4;    // MFMA C/D
typedef unsigned int uint;

union pk { uint4 u; short8 s; };
__device__ __forceinline__ short8 as_s8(uint4 u) { pk p; p.u = u; return p.s; }

__device__ __forceinline__ float wave_sum(float v) {
#pragma unroll
    for (int off = 32; off > 0; off >>= 1) v += __shfl_xor(v, off, 64);
    return v;
}
__device__ __forceinline__ float wave_max(float v) {
#pragma unroll
    for (int off = 32; off > 0; off >>= 1) v = fmaxf(v, __shfl_xor(v, off, 64));
    return v;
}

// fp32x8 -> bf16 hi/lo fragments (truncation split; verified R4-R6) + msq into
// 4 rotating accumulators (breaks the serial fma chain).
__device__ __forceinline__ void cvt_hilo(const float4& a, const float4& b,
                                         short8& hi, short8& lo, float4& msqv) {
    float xs[8] = {a.x, a.y, a.z, a.w, b.x, b.y, b.z, b.w};
    float* mq = &msqv.x;
    uint lu[8];
#pragma unroll
    for (int j = 0; j < 8; ++j) {
        uint u = __float_as_uint(xs[j]);
        float lof = xs[j] - __uint_as_float(u & 0xffff0000u);
        lu[j] = __float_as_uint(lof);
        mq[j & 3] = fmaf(xs[j], xs[j], mq[j & 3]);
    }
    uint4 h, l;
    h.x = __builtin_amdgcn_perm(__float_as_uint(xs[1]), __float_as_uint(xs[0]), SELHI);
    h.y = __builtin_amdgcn_perm(__float_as_uint(xs[3]), __float_as_uint(xs[2]), SELHI);
    h.z = __builtin_amdgcn_perm(__float_as_uint(xs[5]), __float_as_uint(xs[4]), SELHI);
    h.w = __builtin_amdgcn_perm(__float_as_uint(xs[7]), __float_as_uint(xs[6]), SELHI);
    l.x = __builtin_amdgcn_perm(lu[1], lu[0], SELHI);
    l.y = __builtin_amdgcn_perm(lu[3], lu[2], SELHI);
    l.z = __builtin_amdgcn_perm(lu[5], lu[4], SELHI);
    l.w = __builtin_amdgcn_perm(lu[7], lu[6], SELHI);
    hi = as_s8(h); lo = as_s8(l);
}

// ---------------------------------------------------------------------------
// k_split: key fp32 -> bf16 hi/lo planes in MFMA A-frag order; fuses the
// per-b ||key||^2 reduction into kn2[16] (zeroed before launch).
// ---------------------------------------------------------------------------
__global__ void k_split(const float* __restrict__ key, unsigned short* __restrict__ ksw,
                        float* __restrict__ kn2) {
    const int tid  = threadIdx.x;
    const int g    = blockIdx.x * 256 + tid;   // 0 .. NT*64-1
    const int tile = g >> 6, lane = g & 63;
    const int m = lane & 15, quad = lane >> 4;
    const float* src = key + (size_t)m * D + tile * 32 + quad * 8;
    float4 x0 = *(const float4*)src;
    float4 x1 = *(const float4*)(src + 4);
    short8 hi, lo;
    float4 msqv = {0.f, 0.f, 0.f, 0.f};
    cvt_hilo(x0, x1, hi, lo, msqv);
    pk ph; ph.s = hi;
    pk pl; pl.s = lo;
    *(uint4*)(ksw + ((size_t)tile * 64 + lane) * 8)        = ph.u;
    *(uint4*)(ksw + ((size_t)(NT + tile) * 64 + lane) * 8) = pl.u;

    float ssq = (msqv.x + msqv.y) + (msqv.z + msqv.w);
    ssq += __shfl_xor(ssq, 16, 64);
    ssq += __shfl_xor(ssq, 32, 64);
    __shared__ float lds[4][16];
    if (quad == 0) lds[tid >> 6][m] = ssq;
    __syncthreads();
    if (tid < 16)
        atomicAdd(&kn2[tid], lds[0][tid] + lds[1][tid] + lds[2][tid] + lds[3][tid]);
}

// ---------------------------------------------------------------------------
// k_dots (MFMA): dots[b][n] += key[b].mem[n] (this wave's K-chunk),
// mn2[n] += ||mem[n]||^2 chunk. Grid (125, 7) x 4 waves; depth-2 register
// pipeline. Results go straight to dots/mn2 with fp32 HW atomics (28-way
// contention per address) -- no dpart buffer, no gather in softmax.
// R0: launch_bounds 2 -> 3 blocks/CU (VGPR cap 256 -> 170; est. pressure
// ~140). 3 waves/SIMD x ~450cy compute now covers ~900cy HBM latency.
// ---------------------------------------------------------------------------
__global__ __launch_bounds__(256, 3) void k_dots(const float* __restrict__ mem,
                                                 const unsigned short* __restrict__ ksw,
                                                 float* __restrict__ dots,
                                                 float* __restrict__ mn2) {
    const int tid  = threadIdx.x;
    const int lane = tid & 63;
    const int wave = tid >> 6;
    const int n0   = blockIdx.x * 16;
    const int kc   = blockIdx.y * 4 + wave;        // 0..27
    const int nrow = lane & 15, quad = lane >> 4;

    const float4* mrow4 = (const float4*)(mem + (size_t)(n0 + nrow) * D + kc * KSPAN) + quad * 2;
    const uint4* khp = (const uint4*)(ksw + ((size_t)(kc * KTILES) * 64 + lane) * 8);
    const uint4* klp = (const uint4*)(ksw + ((size_t)(NT + kc * KTILES) * 64 + lane) * 8);

    f32x4 ahh = {0.f, 0.f, 0.f, 0.f};
    f32x4 ahl = ahh, alh = ahh;
    float4 msqv = {0.f, 0.f, 0.f, 0.f};

    float4 a0 = mrow4[0], a1 = mrow4[1];
    uint4  ha = khp[0],   la = klp[0];
    float4 b0 = mrow4[8], b1 = mrow4[9];
    uint4  hb = khp[64],  lb = klp[64];

    for (int t = 0; t < KTILES; t += 2) {
        const int t2 = (t + 2 < KTILES) ? t + 2 : t;
        const int t3 = (t + 3 < KTILES) ? t + 3 : t;
        float4 na0 = mrow4[(size_t)t2 * 8], na1 = mrow4[(size_t)t2 * 8 + 1];
        uint4  nha = khp[(size_t)t2 * 64],  nla = klp[(size_t)t2 * 64];
        float4 nb0 = mrow4[(size_t)t3 * 8], nb1 = mrow4[(size_t)t3 * 8 + 1];
        uint4  nhb = khp[(size_t)t3 * 64],  nlb = klp[(size_t)t3 * 64];

        short8 bh, bl;
        cvt_hilo(a0, a1, bh, bl, msqv);
        {
            short8 kh = as_s8(ha), kl = as_s8(la);
            ahh = __builtin_amdgcn_mfma_f32_16x16x32_bf16(kh, bh, ahh, 0, 0, 0);
            ahl = __builtin_amdgcn_mfma_f32_16x16x32_bf16(kh, bl, ahl, 0, 0, 0);
            alh = __builtin_amdgcn_mfma_f32_16x16x32_bf16(kl, bh, alh, 0, 0, 0);
        }
        cvt_hilo(b0, b1, bh, bl, msqv);
        {
            short8 kh = as_s8(hb), kl = as_s8(lb);
            ahh = __builtin_amdgcn_mfma_f32_16x16x32_bf16(kh, bh, ahh, 0, 0, 0);
            ahl = __builtin_amdgcn_mfma_f32_16x16x32_bf16(kh, bl, ahl, 0, 0, 0);
            alh = __builtin_amdgcn_mfma_f32_16x16x32_bf16(kl, bh, alh, 0, 0, 0);
        }
        a0 = na0; a1 = na1; ha = nha; la = nla;
        b0 = nb0; b1 = nb1; hb = nhb; lb = nlb;
    }

    // C/D layout (m89-verified): col(n) = lane&15, row(b) = quad*4 + reg
#pragma unroll
    for (int r = 0; r < 4; ++r)
        unsafeAtomicAdd(&dots[(size_t)(quad * 4 + r) * N + n0 + nrow],
                        ahh[r] + ahl[r] + alh[r]);

    float msq = (msqv.x + msqv.y) + (msqv.z + msqv.w);
    msq += __shfl_xor(msq, 16, 64);
    msq += __shfl_xor(msq, 32, 64);
    if (quad == 0) unsafeAtomicAdd(&mn2[n0 + nrow], msq);
}

// ---------------------------------------------------------------------------
// k_softmax: per-b softmax of tan(cos * PI/2) from pre-reduced dots/mn2.
// Small coalesced reads only (~136 KB total).
// ---------------------------------------------------------------------------
__global__ __launch_bounds__(256, 2) void k_softmax(const float* __restrict__ kn2,
                                                    const float* __restrict__ dots,
                                                    const float* __restrict__ mn2,
                                                    float* __restrict__ w) {
    const int b = blockIdx.x, tid = threadIdx.x;
    const int wv = tid >> 6, ln = tid & 63;
    __shared__ float t[N];
    __shared__ float redB[4], redC[4];

    const float kn = fmaxf(sqrtf(kn2[b]), 1e-8f);

    float mx = -1e30f;
    for (int n = tid; n < N; n += 256) {
        float mn = fmaxf(sqrtf(mn2[n]), 1e-8f);
        float tv = tanf(dots[(size_t)b * N + n] / (kn * mn) * PI2);
        t[n] = tv;
        mx = fmaxf(mx, tv);
    }
    mx = wave_max(mx);
    if (ln == 0) redB[wv] = mx;
    __syncthreads();
    mx = fmaxf(fmaxf(redB[0], redB[1]), fmaxf(redB[2], redB[3]));

    float sum = 0.f;
    for (int n = tid; n < N; n += 256) {
        float e = expf(t[n] - mx);
        t[n] = e;
        sum += e;
    }
    sum = wave_sum(sum);
    if (ln == 0) redC[wv] = sum;
    __syncthreads();
    sum = redC[0] + redC[1] + redC[2] + redC[3];
    const float inv = 1.f / sum;
    for (int n = tid; n < N; n += 256) w[(size_t)b * N + n] = t[n] * inv;
}

// ---------------------------------------------------------------------------
// k_out partials: part[c][b][d] = sum_{n in chunk c} w[b][n]*mem[n][d].
// R0: grid (25, 20) = 500 blocks -> single occupancy round (no 113-block
// tail). Group-of-4 depth-2 pipeline (cur/nxt 32 VGPR instead of 64) drops
// est. pressure to ~115 -> launch_bounds(256,3) = 12 waves/CU. w read from
// LDS as one broadcast float4 per (b, group).
// ---------------------------------------------------------------------------
__global__ __launch_bounds__(256, 3) void k_out_p(const float4* __restrict__ mem,
                                                  const float* __restrict__ w,
                                                  float4* __restrict__ part) {
    const int tid = threadIdx.x;
    const int d4  = blockIdx.x * 256 + tid;
    const int n0  = blockIdx.y * NPER;

    __shared__ float wt[B * NPER];   // 16 x 100
    for (int i = tid; i < B * NPER; i += 256)
        wt[i] = w[(size_t)(i / NPER) * N + n0 + (i % NPER)];
    __syncthreads();
    if (d4 >= D4) return;

    const float4* mp = mem + (size_t)n0 * D4 + d4;
    float4 acc[B];
#pragma unroll
    for (int b = 0; b < B; ++b) acc[b] = make_float4(0.f, 0.f, 0.f, 0.f);

    float4 cur[4];
#pragma unroll
    for (int u = 0; u < 4; ++u) cur[u] = mp[(size_t)u * D4];

    for (int g = 0; g < NPER / 4; ++g) {     // 25 groups of 4
        const int gn = (g + 1 < NPER / 4) ? g + 1 : g;
        float4 nxt[4];
#pragma unroll
        for (int u = 0; u < 4; ++u) nxt[u] = mp[(size_t)(gn * 4 + u) * D4];
#pragma unroll
        for (int b = 0; b < B; ++b) {
            const float4 wv = *((const float4*)(wt + b * NPER) + g);
            float4 a = acc[b];
            a.x = fmaf(wv.x, cur[0].x, a.x); a.y = fmaf(wv.x, cur[0].y, a.y);
            a.z = fmaf(wv.x, cur[0].z, a.z); a.w = fmaf(wv.x, cur[0].w, a.w);
            a.x = fmaf(wv.y, cur[1].x, a.x); a.y = fmaf(wv.y, cur[1].y, a.y);
            a.z = fmaf(wv.y, cur[1].z, a.z); a.w = fmaf(wv.y, cur[1].w, a.w);
            a.x = fmaf(wv.z, cur[2].x, a.x); a.y = fmaf(wv.z, cur[2].y, a.y);
            a.z = fmaf(wv.z, cur[2].z, a.z); a.w = fmaf(wv.z, cur[2].w, a.w);
            a.x = fmaf(wv.w, cur[3].x, a.x); a.y = fmaf(wv.w, cur[3].y, a.y);
            a.z = fmaf(wv.w, cur[3].z, a.z); a.w = fmaf(wv.w, cur[3].w, a.w);
            acc[b] = a;
        }
#pragma unroll
        for (int u = 0; u < 4; ++u) cur[u] = nxt[u];
    }
#pragma unroll
    for (int b = 0; b < B; ++b)
        part[((size_t)blockIdx.y * B + b) * D4 + d4] = acc[b];
}

__global__ void k_reduce(const float4* __restrict__ part, float4* __restrict__ out) {
    const int i = blockIdx.x * 256 + threadIdx.x;   // < B*D4 = 100352
    float4 s = part[i];
#pragma unroll
    for (int c = 1; c < NCHUNK; ++c) {
        float4 p = part[(size_t)c * B * D4 + i];
        s.x += p.x; s.y += p.y; s.z += p.z; s.w += p.w;
    }
    out[i] = s;
}

// Atomic fallback if workspace is too small for partials.
__global__ __launch_bounds__(256, 2) void k_out_atomic(const float4* __restrict__ mem,
                                                       const float* __restrict__ w,
                                                       float* __restrict__ out) {
    const int tid = threadIdx.x;
    const int d4  = blockIdx.x * 256 + tid;
    const int n0  = blockIdx.y * NPER;
    __shared__ float wt[B * NPER];
    for (int i = tid; i < B * NPER; i += 256)
        wt[i] = w[(size_t)(i / NPER) * N + n0 + (i % NPER)];
    __syncthreads();
    if (d4 >= D4) return;
    const float4* mp = mem + (size_t)n0 * D4 + d4;
    float4 acc[B];
#pragma unroll
    for (int b = 0; b < B; ++b) acc[b] = make_float4(0.f, 0.f, 0.f, 0.f);
    for (int n = 0; n < NPER; n += 4) {
        float4 mv[4];
#pragma unroll
        for (int u = 0; u < 4; ++u) mv[u] = mp[(size_t)(n + u) * D4];
#pragma unroll
        for (int b = 0; b < B; ++b) {
            float4 a = acc[b];
#pragma unroll
            for (int u = 0; u < 4; ++u) {
                const float wv = wt[b * NPER + n + u];
                a.x = fmaf(wv, mv[u].x, a.x); a.y = fmaf(wv, mv[u].y, a.y);
                a.z = fmaf(wv, mv[u].z, a.z); a.w = fmaf(wv, mv[u].w, a.w);
            }
            acc[b] = a;
        }
    }
#pragma unroll
    for (int b = 0; b < B; ++b) {
        float* op = out + (size_t)b * D + (size_t)d4 * 4;
        unsafeAtomicAdd(op + 0, acc[b].x);
        unsafeAtomicAdd(op + 1, acc[b].y);
        unsafeAtomicAdd(op + 2, acc[b].z);
        unsafeAtomicAdd(op + 3, acc[b].w);
    }
}

extern "C" void kernel_launch(void* const* d_in, const int* in_sizes, int n_in,
                              void* d_out, int out_size, void* d_ws, size_t ws_size,
                              hipStream_t stream) {
    const float* key = (const float*)d_in[0];   // [16, 512, 7, 7]
    const float* mem = (const float*)d_in[1];   // [2000, 512, 7, 7]
    float* out = (float*)d_out;                 // [16, 512, 7, 7]

    // Workspace layout (floats), 16B-aligned sections.
    float* ws = (float*)d_ws;
    unsigned short* ksw = (unsigned short*)ws;          // 2*NT*64*8 ush = 401408 fl
    float* dots  = ws + 401408;                         // B*N = 32000
    float* mn2   = dots + (size_t)B * N;                // N   =  2000
    float* kn2   = mn2 + N;                             // 16
    float* w     = kn2 + 16;                            // B*N =  32000
    float* part  = w + (size_t)B * N;                   // NCHUNK*B*D = 8028160
    const size_t need_full =
        (size_t)(401408 + B * N + N + 16 + B * N + (size_t)NCHUNK * B * D) * 4;

    // One memset zeroes dots + mn2 + kn2 (contiguous, 136 KB).
    hipMemsetAsync(dots, 0, (size_t)(B * N + N + 16) * sizeof(float), stream);
    k_split<<<dim3(NT * 64 / 256), 256, 0, stream>>>(key, ksw, kn2);
    k_dots<<<dim3(N / 16, KC / 4), 256, 0, stream>>>(mem, ksw, dots, mn2);
    k_softmax<<<dim3(B), 256, 0, stream>>>(kn2, dots, mn2, w);
    if (ws_size >= need_full) {
        k_out_p<<<dim3((D4 + 255) / 256, NCHUNK), 256, 0, stream>>>((const float4*)mem, w, (float4*)part);
        k_reduce<<<dim3(B * D4 / 256), 256, 0, stream>>>((const float4*)part, (float4*)out);
    } else {
        hipMemsetAsync(d_out, 0, (size_t)B * D * sizeof(float), stream);
        k_out_atomic<<<dim3((D4 + 255) / 256, NCHUNK), 256, 0, stream>>>((const float4*)mem, w, out);
    }
}

// Round 2
// 332.368 us; speedup vs baseline: 1.0294x; 1.0121x over previous
//
#include <hip/hip_runtime.h>
#include <hip/hip_fp16.h>
#include <math.h>

#define B 16
#define N 2000
#define D 25088            // 512*7*7
#define D4 6272            // D/4
#define PI2 1.570795f      // 3.14159/2, matches the torch-module constant
#define KC 28              // K-chunks in k_dots (7 block-y x 4 waves)
#define KSPAN (D / KC)     // 896
#define KTILES (KSPAN / 32)// 28 MFMA k-steps per wave
#define NT (D / 32)        // 784 k-tiles total
#define KBLK (NT / 4)      // 196 k_split blocks (4 tiles each)
#define NCHUNK 20          // grid (25,20)=500 blocks, single occupancy round
#define NPER (N / NCHUNK)  // 100
#define SELHI 0x07060302u  // v_perm selector: pack hi16(x0)|hi16(x1)<<16
#define PSCALE 1048576.0f  // 2^20: part partials [0,~1e-4] -> [0,~105] in f16
#define PINV   (1.0f / 1048576.0f)

typedef __attribute__((ext_vector_type(8))) short short8;   // 8 x bf16 frag
typedef __attribute__((ext_vector_type(4))) float f32x4;    // MFMA C/D
typedef unsigned int uint;

union pk { uint4 u; short8 s; };
__device__ __forceinline__ short8 as_s8(uint4 u) { pk p; p.u = u; return p.s; }
union hpk { __half2 h; uint u; };

__device__ __forceinline__ float wave_sum(float v) {
#pragma unroll
    for (int off = 32; off > 0; off >>= 1) v += __shfl_xor(v, off, 64);
    return v;
}
__device__ __forceinline__ float wave_max(float v) {
#pragma unroll
    for (int off = 32; off > 0; off >>= 1) v = fmaxf(v, __shfl_xor(v, off, 64));
    return v;
}

// fp32x8 -> bf16 hi/lo fragments (truncation split; verified R4-R6) + msq into
// 4 rotating accumulators (breaks the serial fma chain).
__device__ __forceinline__ void cvt_hilo(const float4& a, const float4& b,
                                         short8& hi, short8& lo, float4& msqv) {
    float xs[8] = {a.x, a.y, a.z, a.w, b.x, b.y, b.z, b.w};
    float* mq = &msqv.x;
    uint lu[8];
#pragma unroll
    for (int j = 0; j < 8; ++j) {
        uint u = __float_as_uint(xs[j]);
        float lof = xs[j] - __uint_as_float(u & 0xffff0000u);
        lu[j] = __float_as_uint(lof);
        mq[j & 3] = fmaf(xs[j], xs[j], mq[j & 3]);
    }
    uint4 h, l;
    h.x = __builtin_amdgcn_perm(__float_as_uint(xs[1]), __float_as_uint(xs[0]), SELHI);
    h.y = __builtin_amdgcn_perm(__float_as_uint(xs[3]), __float_as_uint(xs[2]), SELHI);
    h.z = __builtin_amdgcn_perm(__float_as_uint(xs[5]), __float_as_uint(xs[4]), SELHI);
    h.w = __builtin_amdgcn_perm(__float_as_uint(xs[7]), __float_as_uint(xs[6]), SELHI);
    l.x = __builtin_amdgcn_perm(lu[1], lu[0], SELHI);
    l.y = __builtin_amdgcn_perm(lu[3], lu[2], SELHI);
    l.z = __builtin_amdgcn_perm(lu[5], lu[4], SELHI);
    l.w = __builtin_amdgcn_perm(lu[7], lu[6], SELHI);
    hi = as_s8(h); lo = as_s8(l);
}

// ---------------------------------------------------------------------------
// k_split: key fp32 -> bf16 hi/lo planes in MFMA A-frag order.
// R1: also zeroes dots+mn2 (34,000 floats, replaces the hipMemsetAsync
// dispatch; stream-ordered before k_dots' atomics) and writes a
// DETERMINISTIC per-block ||key_b||^2 partial to kpart[196][16] (replaces
// kn2 atomics; summed in k_softmax).
// ---------------------------------------------------------------------------
__global__ void k_split(const float* __restrict__ key, unsigned short* __restrict__ ksw,
                        float* __restrict__ zdst, float* __restrict__ kpart) {
    const int tid  = threadIdx.x;
    const int bx   = blockIdx.x;
    const int g    = bx * 256 + tid;   // 0 .. NT*64-1
    if (g < B * N + N) zdst[g] = 0.f;  // zero dots (32000) + mn2 (2000)
    const int tile = g >> 6, lane = g & 63;
    const int m = lane & 15, quad = lane >> 4;
    const float* src = key + (size_t)m * D + tile * 32 + quad * 8;
    float4 x0 = *(const float4*)src;
    float4 x1 = *(const float4*)(src + 4);
    short8 hi, lo;
    float4 msqv = {0.f, 0.f, 0.f, 0.f};
    cvt_hilo(x0, x1, hi, lo, msqv);
    pk ph; ph.s = hi;
    pk pl; pl.s = lo;
    *(uint4*)(ksw + ((size_t)tile * 64 + lane) * 8)        = ph.u;
    *(uint4*)(ksw + ((size_t)(NT + tile) * 64 + lane) * 8) = pl.u;

    float ssq = (msqv.x + msqv.y) + (msqv.z + msqv.w);
    ssq += __shfl_xor(ssq, 16, 64);
    ssq += __shfl_xor(ssq, 32, 64);
    __shared__ float lds[4][16];
    if (quad == 0) lds[tid >> 6][m] = ssq;
    __syncthreads();
    if (tid < 16)
        kpart[bx * 16 + tid] = lds[0][tid] + lds[1][tid] + lds[2][tid] + lds[3][tid];
}

// ---------------------------------------------------------------------------
// k_dots (MFMA): dots[b][n] += key[b].mem[n] (this wave's K-chunk),
// mn2[n] += ||mem[n]||^2 chunk. Grid (125, 7) x 4 waves; depth-2 register
// pipeline. Results go straight to dots/mn2 with fp32 HW atomics (28-way
// contention per address).
// ---------------------------------------------------------------------------
__global__ __launch_bounds__(256, 3) void k_dots(const float* __restrict__ mem,
                                                 const unsigned short* __restrict__ ksw,
                                                 float* __restrict__ dots,
                                                 float* __restrict__ mn2) {
    const int tid  = threadIdx.x;
    const int lane = tid & 63;
    const int wave = tid >> 6;
    const int n0   = blockIdx.x * 16;
    const int kc   = blockIdx.y * 4 + wave;        // 0..27
    const int nrow = lane & 15, quad = lane >> 4;

    const float4* mrow4 = (const float4*)(mem + (size_t)(n0 + nrow) * D + kc * KSPAN) + quad * 2;
    const uint4* khp = (const uint4*)(ksw + ((size_t)(kc * KTILES) * 64 + lane) * 8);
    const uint4* klp = (const uint4*)(ksw + ((size_t)(NT + kc * KTILES) * 64 + lane) * 8);

    f32x4 ahh = {0.f, 0.f, 0.f, 0.f};
    f32x4 ahl = ahh, alh = ahh;
    float4 msqv = {0.f, 0.f, 0.f, 0.f};

    float4 a0 = mrow4[0], a1 = mrow4[1];
    uint4  ha = khp[0],   la = klp[0];
    float4 b0 = mrow4[8], b1 = mrow4[9];
    uint4  hb = khp[64],  lb = klp[64];

    for (int t = 0; t < KTILES; t += 2) {
        const int t2 = (t + 2 < KTILES) ? t + 2 : t;
        const int t3 = (t + 3 < KTILES) ? t + 3 : t;
        float4 na0 = mrow4[(size_t)t2 * 8], na1 = mrow4[(size_t)t2 * 8 + 1];
        uint4  nha = khp[(size_t)t2 * 64],  nla = klp[(size_t)t2 * 64];
        float4 nb0 = mrow4[(size_t)t3 * 8], nb1 = mrow4[(size_t)t3 * 8 + 1];
        uint4  nhb = khp[(size_t)t3 * 64],  nlb = klp[(size_t)t3 * 64];

        short8 bh, bl;
        cvt_hilo(a0, a1, bh, bl, msqv);
        {
            short8 kh = as_s8(ha), kl = as_s8(la);
            ahh = __builtin_amdgcn_mfma_f32_16x16x32_bf16(kh, bh, ahh, 0, 0, 0);
            ahl = __builtin_amdgcn_mfma_f32_16x16x32_bf16(kh, bl, ahl, 0, 0, 0);
            alh = __builtin_amdgcn_mfma_f32_16x16x32_bf16(kl, bh, alh, 0, 0, 0);
        }
        cvt_hilo(b0, b1, bh, bl, msqv);
        {
            short8 kh = as_s8(hb), kl = as_s8(lb);
            ahh = __builtin_amdgcn_mfma_f32_16x16x32_bf16(kh, bh, ahh, 0, 0, 0);
            ahl = __builtin_amdgcn_mfma_f32_16x16x32_bf16(kh, bl, ahl, 0, 0, 0);
            alh = __builtin_amdgcn_mfma_f32_16x16x32_bf16(kl, bh, alh, 0, 0, 0);
        }
        a0 = na0; a1 = na1; ha = nha; la = nla;
        b0 = nb0; b1 = nb1; hb = nhb; lb = nlb;
    }

    // C/D layout (m89-verified): col(n) = lane&15, row(b) = quad*4 + reg
#pragma unroll
    for (int r = 0; r < 4; ++r)
        unsafeAtomicAdd(&dots[(size_t)(quad * 4 + r) * N + n0 + nrow],
                        ahh[r] + ahl[r] + alh[r]);

    float msq = (msqv.x + msqv.y) + (msqv.z + msqv.w);
    msq += __shfl_xor(msq, 16, 64);
    msq += __shfl_xor(msq, 32, 64);
    if (quad == 0) unsafeAtomicAdd(&mn2[n0 + nrow], msq);
}

// ---------------------------------------------------------------------------
// k_softmax: per-b softmax of tan(cos * PI/2). R1: first sums the 196
// deterministic kpart partials to get ||key_b||^2 (replaces kn2 atomics).
// ---------------------------------------------------------------------------
__global__ __launch_bounds__(256, 2) void k_softmax(const float* __restrict__ kpart,
                                                    const float* __restrict__ dots,
                                                    const float* __restrict__ mn2,
                                                    float* __restrict__ w) {
    const int b = blockIdx.x, tid = threadIdx.x;
    const int wv = tid >> 6, ln = tid & 63;
    __shared__ float t[N];
    __shared__ float redB[4], redC[4];

    // kn2 = sum of 196 block partials for this b
    float s = (tid < KBLK) ? kpart[tid * 16 + b] : 0.f;
    s = wave_sum(s);
    if (ln == 0) redB[wv] = s;
    __syncthreads();
    const float kn = fmaxf(sqrtf(redB[0] + redB[1] + redB[2] + redB[3]), 1e-8f);
    __syncthreads();   // redB is reused below

    float mx = -1e30f;
    for (int n = tid; n < N; n += 256) {
        float mn = fmaxf(sqrtf(mn2[n]), 1e-8f);
        float tv = tanf(dots[(size_t)b * N + n] / (kn * mn) * PI2);
        t[n] = tv;
        mx = fmaxf(mx, tv);
    }
    mx = wave_max(mx);
    if (ln == 0) redB[wv] = mx;
    __syncthreads();
    mx = fmaxf(fmaxf(redB[0], redB[1]), fmaxf(redB[2], redB[3]));

    float sum = 0.f;
    for (int n = tid; n < N; n += 256) {
        float e = expf(t[n] - mx);
        t[n] = e;
        sum += e;
    }
    sum = wave_sum(sum);
    if (ln == 0) redC[wv] = sum;
    __syncthreads();
    sum = redC[0] + redC[1] + redC[2] + redC[3];
    const float inv = 1.f / sum;
    for (int n = tid; n < N; n += 256) w[(size_t)b * N + n] = t[n] * inv;
}

// ---------------------------------------------------------------------------
// k_out partials: part[c][b][d4] = sum_{n in chunk c} w[b][n]*mem[n][d4..+3].
// R1: part stored as scaled f16x4 (uint2) -- halves the part round-trip
// (64 -> 32 MB). Values are positive sums in [0,~1e-4]; x2^20 puts them in
// [0,~105], RNE f16 rel err 2^-11 -> ~2e-8 added output error.
// Occupancy 3 -> 4 blocks/CU (est. ~115 VGPR < 128 cap).
// ---------------------------------------------------------------------------
__global__ __launch_bounds__(256, 4) void k_out_p(const float4* __restrict__ mem,
                                                  const float* __restrict__ w,
                                                  uint2* __restrict__ part) {
    const int tid = threadIdx.x;
    const int d4  = blockIdx.x * 256 + tid;
    const int n0  = blockIdx.y * NPER;

    __shared__ float wt[B * NPER];   // 16 x 100
    for (int i = tid; i < B * NPER; i += 256)
        wt[i] = w[(size_t)(i / NPER) * N + n0 + (i % NPER)];
    __syncthreads();
    if (d4 >= D4) return;

    const float4* mp = mem + (size_t)n0 * D4 + d4;
    float4 acc[B];
#pragma unroll
    for (int b = 0; b < B; ++b) acc[b] = make_float4(0.f, 0.f, 0.f, 0.f);

    float4 cur[4];
#pragma unroll
    for (int u = 0; u < 4; ++u) cur[u] = mp[(size_t)u * D4];

    for (int g = 0; g < NPER / 4; ++g) {     // 25 groups of 4
        const int gn = (g + 1 < NPER / 4) ? g + 1 : g;
        float4 nxt[4];
#pragma unroll
        for (int u = 0; u < 4; ++u) nxt[u] = mp[(size_t)(gn * 4 + u) * D4];
#pragma unroll
        for (int b = 0; b < B; ++b) {
            const float4 wv = *((const float4*)(wt + b * NPER) + g);
            float4 a = acc[b];
            a.x = fmaf(wv.x, cur[0].x, a.x); a.y = fmaf(wv.x, cur[0].y, a.y);
            a.z = fmaf(wv.x, cur[0].z, a.z); a.w = fmaf(wv.x, cur[0].w, a.w);
            a.x = fmaf(wv.y, cur[1].x, a.x); a.y = fmaf(wv.y, cur[1].y, a.y);
            a.z = fmaf(wv.y, cur[1].z, a.z); a.w = fmaf(wv.y, cur[1].w, a.w);
            a.x = fmaf(wv.z, cur[2].x, a.x); a.y = fmaf(wv.z, cur[2].y, a.y);
            a.z = fmaf(wv.z, cur[2].z, a.z); a.w = fmaf(wv.z, cur[2].w, a.w);
            a.x = fmaf(wv.w, cur[3].x, a.x); a.y = fmaf(wv.w, cur[3].y, a.y);
            a.z = fmaf(wv.w, cur[3].z, a.z); a.w = fmaf(wv.w, cur[3].w, a.w);
            acc[b] = a;
        }
#pragma unroll
        for (int u = 0; u < 4; ++u) cur[u] = nxt[u];
    }
#pragma unroll
    for (int b = 0; b < B; ++b) {
        hpk p0, p1;
        p0.h = __floats2half2_rn(acc[b].x * PSCALE, acc[b].y * PSCALE);
        p1.h = __floats2half2_rn(acc[b].z * PSCALE, acc[b].w * PSCALE);
        uint2 v; v.x = p0.u; v.y = p1.u;
        part[((size_t)blockIdx.y * B + b) * D4 + d4] = v;
    }
}

__global__ void k_reduce(const uint2* __restrict__ part, float4* __restrict__ out) {
    const int i = blockIdx.x * 256 + threadIdx.x;   // < B*D4 = 100352
    float sx = 0.f, sy = 0.f, sz = 0.f, sw = 0.f;
#pragma unroll
    for (int c = 0; c < NCHUNK; ++c) {
        uint2 v = part[(size_t)c * B * D4 + i];
        hpk a, b2; a.u = v.x; b2.u = v.y;
        float2 f0 = __half22float2(a.h), f1 = __half22float2(b2.h);
        sx += f0.x; sy += f0.y; sz += f1.x; sw += f1.y;
    }
    out[i] = make_float4(sx * PINV, sy * PINV, sz * PINV, sw * PINV);
}

// Atomic fallback if workspace is too small for partials (fp32 path).
__global__ __launch_bounds__(256, 2) void k_out_atomic(const float4* __restrict__ mem,
                                                       const float* __restrict__ w,
                                                       float* __restrict__ out) {
    const int tid = threadIdx.x;
    const int d4  = blockIdx.x * 256 + tid;
    const int n0  = blockIdx.y * NPER;
    __shared__ float wt[B * NPER];
    for (int i = tid; i < B * NPER; i += 256)
        wt[i] = w[(size_t)(i / NPER) * N + n0 + (i % NPER)];
    __syncthreads();
    if (d4 >= D4) return;
    const float4* mp = mem + (size_t)n0 * D4 + d4;
    float4 acc[B];
#pragma unroll
    for (int b = 0; b < B; ++b) acc[b] = make_float4(0.f, 0.f, 0.f, 0.f);
    for (int n = 0; n < NPER; n += 4) {
        float4 mv[4];
#pragma unroll
        for (int u = 0; u < 4; ++u) mv[u] = mp[(size_t)(n + u) * D4];
#pragma unroll
        for (int b = 0; b < B; ++b) {
            float4 a = acc[b];
#pragma unroll
            for (int u = 0; u < 4; ++u) {
                const float wv = wt[b * NPER + n + u];
                a.x = fmaf(wv, mv[u].x, a.x); a.y = fmaf(wv, mv[u].y, a.y);
                a.z = fmaf(wv, mv[u].z, a.z); a.w = fmaf(wv, mv[u].w, a.w);
            }
            acc[b] = a;
        }
    }
#pragma unroll
    for (int b = 0; b < B; ++b) {
        float* op = out + (size_t)b * D + (size_t)d4 * 4;
        unsafeAtomicAdd(op + 0, acc[b].x);
        unsafeAtomicAdd(op + 1, acc[b].y);
        unsafeAtomicAdd(op + 2, acc[b].z);
        unsafeAtomicAdd(op + 3, acc[b].w);
    }
}

extern "C" void kernel_launch(void* const* d_in, const int* in_sizes, int n_in,
                              void* d_out, int out_size, void* d_ws, size_t ws_size,
                              hipStream_t stream) {
    const float* key = (const float*)d_in[0];   // [16, 512, 7, 7]
    const float* mem = (const float*)d_in[1];   // [2000, 512, 7, 7]
    float* out = (float*)d_out;                 // [16, 512, 7, 7]

    // Workspace layout (floats), 16B-aligned sections.
    float* ws = (float*)d_ws;
    unsigned short* ksw = (unsigned short*)ws;          // 2*NT*64*8 ush = 401408 fl
    float* dots  = ws + 401408;                         // B*N  = 32000
    float* mn2   = dots + (size_t)B * N;                // N    =  2000  (contiguous after dots)
    float* kpart = mn2 + N;                             // KBLK*16 = 3136
    float* w     = kpart + (size_t)KBLK * 16;           // B*N  = 32000
    float* part  = w + (size_t)B * N;                   // NCHUNK*B*D4 uint2 = NCHUNK*B*D4*2 fl
    const size_t need_full =
        (size_t)(401408 + B * N + N + KBLK * 16 + B * N + (size_t)NCHUNK * B * D4 * 2) * 4;

    // R1: no memset dispatch -- k_split zeroes dots+mn2; kpart is written
    // deterministically (no atomics on it).
    k_split<<<dim3(KBLK), 256, 0, stream>>>(key, ksw, dots, kpart);
    k_dots<<<dim3(N / 16, KC / 4), 256, 0, stream>>>(mem, ksw, dots, mn2);
    k_softmax<<<dim3(B), 256, 0, stream>>>(kpart, dots, mn2, w);
    if (ws_size >= need_full) {
        k_out_p<<<dim3((D4 + 255) / 256, NCHUNK), 256, 0, stream>>>((const float4*)mem, w, (uint2*)part);
        k_reduce<<<dim3(B * D4 / 256), 256, 0, stream>>>((const uint2*)part, (float4*)out);
    } else {
        hipMemsetAsync(d_out, 0, (size_t)B * D * sizeof(float), stream);
        k_out_atomic<<<dim3((D4 + 255) / 256, NCHUNK), 256, 0, stream>>>((const float4*)mem, w, out);
    }
}

// Round 3
// 332.275 us; speedup vs baseline: 1.0297x; 1.0003x over previous
//
#include <hip/hip_runtime.h>
#include <hip/hip_fp16.h>
#include <math.h>

#define B 16
#define N 2000
#define D 25088            // 512*7*7
#define D4 6272            // D/4
#define PI2 1.570795f      // 3.14159/2, matches the torch-module constant
#define KC 28              // K-chunks in k_dots (7 block-y x 4 waves)
#define KSPAN (D / KC)     // 896
#define KTILES (KSPAN / 32)// 28 MFMA k-steps per wave
#define NT (D / 32)        // 784 k-tiles total
#define KBLK (NT / 4)      // 196 k_split blocks (4 tiles each)
#define NCHUNK 20          // grid (25,20)=500 blocks, single occupancy round
#define NPER (N / NCHUNK)  // 100
#define SELHI 0x07060302u  // v_perm selector: pack hi16(x0)|hi16(x1)<<16
#define PSCALE 1048576.0f  // 2^20: exp-weighted partials [0,~8e-3] -> [0,~8400] f16
#define PINV   (1.0f / 1048576.0f)

typedef __attribute__((ext_vector_type(8))) short short8;   // 8 x bf16 frag
typedef __attribute__((ext_vector_type(4))) float f32x4;    // MFMA C/D
typedef unsigned int uint;

union pk { uint4 u; short8 s; };
__device__ __forceinline__ short8 as_s8(uint4 u) { pk p; p.u = u; return p.s; }
union hpk { __half2 h; uint u; };

__device__ __forceinline__ float wave_sum(float v) {
#pragma unroll
    for (int off = 32; off > 0; off >>= 1) v += __shfl_xor(v, off, 64);
    return v;
}
__device__ __forceinline__ float wave_max(float v) {
#pragma unroll
    for (int off = 32; off > 0; off >>= 1) v = fmaxf(v, __shfl_xor(v, off, 64));
    return v;
}

// fp32x8 -> bf16 hi/lo fragments (truncation split; verified R4-R6) + msq into
// 4 rotating accumulators (breaks the serial fma chain).
__device__ __forceinline__ void cvt_hilo(const float4& a, const float4& b,
                                         short8& hi, short8& lo, float4& msqv) {
    float xs[8] = {a.x, a.y, a.z, a.w, b.x, b.y, b.z, b.w};
    float* mq = &msqv.x;
    uint lu[8];
#pragma unroll
    for (int j = 0; j < 8; ++j) {
        uint u = __float_as_uint(xs[j]);
        float lof = xs[j] - __uint_as_float(u & 0xffff0000u);
        lu[j] = __float_as_uint(lof);
        mq[j & 3] = fmaf(xs[j], xs[j], mq[j & 3]);
    }
    uint4 h, l;
    h.x = __builtin_amdgcn_perm(__float_as_uint(xs[1]), __float_as_uint(xs[0]), SELHI);
    h.y = __builtin_amdgcn_perm(__float_as_uint(xs[3]), __float_as_uint(xs[2]), SELHI);
    h.z = __builtin_amdgcn_perm(__float_as_uint(xs[5]), __float_as_uint(xs[4]), SELHI);
    h.w = __builtin_amdgcn_perm(__float_as_uint(xs[7]), __float_as_uint(xs[6]), SELHI);
    l.x = __builtin_amdgcn_perm(lu[1], lu[0], SELHI);
    l.y = __builtin_amdgcn_perm(lu[3], lu[2], SELHI);
    l.z = __builtin_amdgcn_perm(lu[5], lu[4], SELHI);
    l.w = __builtin_amdgcn_perm(lu[7], lu[6], SELHI);
    hi = as_s8(h); lo = as_s8(l);
}

// ---------------------------------------------------------------------------
// k_split: key fp32 -> bf16 hi/lo planes in MFMA A-frag order. Also zeroes
// dots+mn2 (replaces a memset dispatch) and writes DETERMINISTIC per-block
// ||key_b||^2 partials to kpart[196][16].
// ---------------------------------------------------------------------------
__global__ void k_split(const float* __restrict__ key, unsigned short* __restrict__ ksw,
                        float* __restrict__ zdst, float* __restrict__ kpart) {
    const int tid  = threadIdx.x;
    const int bx   = blockIdx.x;
    const int g    = bx * 256 + tid;   // 0 .. NT*64-1
    if (g < B * N + N) zdst[g] = 0.f;  // zero dots (32000) + mn2 (2000)
    const int tile = g >> 6, lane = g & 63;
    const int m = lane & 15, quad = lane >> 4;
    const float* src = key + (size_t)m * D + tile * 32 + quad * 8;
    float4 x0 = *(const float4*)src;
    float4 x1 = *(const float4*)(src + 4);
    short8 hi, lo;
    float4 msqv = {0.f, 0.f, 0.f, 0.f};
    cvt_hilo(x0, x1, hi, lo, msqv);
    pk ph; ph.s = hi;
    pk pl; pl.s = lo;
    *(uint4*)(ksw + ((size_t)tile * 64 + lane) * 8)        = ph.u;
    *(uint4*)(ksw + ((size_t)(NT + tile) * 64 + lane) * 8) = pl.u;

    float ssq = (msqv.x + msqv.y) + (msqv.z + msqv.w);
    ssq += __shfl_xor(ssq, 16, 64);
    ssq += __shfl_xor(ssq, 32, 64);
    __shared__ float lds[4][16];
    if (quad == 0) lds[tid >> 6][m] = ssq;
    __syncthreads();
    if (tid < 16)
        kpart[bx * 16 + tid] = lds[0][tid] + lds[1][tid] + lds[2][tid] + lds[3][tid];
}

// ---------------------------------------------------------------------------
// k_dots (MFMA): dots[b][n] += key[b].mem[n] (this wave's K-chunk),
// mn2[n] += ||mem[n]||^2 chunk. Grid (125, 7) x 4 waves; depth-2 register
// pipeline; fp32 HW atomics (28-way contention per address).
// ---------------------------------------------------------------------------
__global__ __launch_bounds__(256, 3) void k_dots(const float* __restrict__ mem,
                                                 const unsigned short* __restrict__ ksw,
                                                 float* __restrict__ dots,
                                                 float* __restrict__ mn2) {
    const int tid  = threadIdx.x;
    const int lane = tid & 63;
    const int wave = tid >> 6;
    const int n0   = blockIdx.x * 16;
    const int kc   = blockIdx.y * 4 + wave;        // 0..27
    const int nrow = lane & 15, quad = lane >> 4;

    const float4* mrow4 = (const float4*)(mem + (size_t)(n0 + nrow) * D + kc * KSPAN) + quad * 2;
    const uint4* khp = (const uint4*)(ksw + ((size_t)(kc * KTILES) * 64 + lane) * 8);
    const uint4* klp = (const uint4*)(ksw + ((size_t)(NT + kc * KTILES) * 64 + lane) * 8);

    f32x4 ahh = {0.f, 0.f, 0.f, 0.f};
    f32x4 ahl = ahh, alh = ahh;
    float4 msqv = {0.f, 0.f, 0.f, 0.f};

    float4 a0 = mrow4[0], a1 = mrow4[1];
    uint4  ha = khp[0],   la = klp[0];
    float4 b0 = mrow4[8], b1 = mrow4[9];
    uint4  hb = khp[64],  lb = klp[64];

    for (int t = 0; t < KTILES; t += 2) {
        const int t2 = (t + 2 < KTILES) ? t + 2 : t;
        const int t3 = (t + 3 < KTILES) ? t + 3 : t;
        float4 na0 = mrow4[(size_t)t2 * 8], na1 = mrow4[(size_t)t2 * 8 + 1];
        uint4  nha = khp[(size_t)t2 * 64],  nla = klp[(size_t)t2 * 64];
        float4 nb0 = mrow4[(size_t)t3 * 8], nb1 = mrow4[(size_t)t3 * 8 + 1];
        uint4  nhb = khp[(size_t)t3 * 64],  nlb = klp[(size_t)t3 * 64];

        short8 bh, bl;
        cvt_hilo(a0, a1, bh, bl, msqv);
        {
            short8 kh = as_s8(ha), kl = as_s8(la);
            ahh = __builtin_amdgcn_mfma_f32_16x16x32_bf16(kh, bh, ahh, 0, 0, 0);
            ahl = __builtin_amdgcn_mfma_f32_16x16x32_bf16(kh, bl, ahl, 0, 0, 0);
            alh = __builtin_amdgcn_mfma_f32_16x16x32_bf16(kl, bh, alh, 0, 0, 0);
        }
        cvt_hilo(b0, b1, bh, bl, msqv);
        {
            short8 kh = as_s8(hb), kl = as_s8(lb);
            ahh = __builtin_amdgcn_mfma_f32_16x16x32_bf16(kh, bh, ahh, 0, 0, 0);
            ahl = __builtin_amdgcn_mfma_f32_16x16x32_bf16(kh, bl, ahl, 0, 0, 0);
            alh = __builtin_amdgcn_mfma_f32_16x16x32_bf16(kl, bh, alh, 0, 0, 0);
        }
        a0 = na0; a1 = na1; ha = nha; la = nla;
        b0 = nb0; b1 = nb1; hb = nhb; lb = nlb;
    }

    // C/D layout (m89-verified): col(n) = lane&15, row(b) = quad*4 + reg
#pragma unroll
    for (int r = 0; r < 4; ++r)
        unsafeAtomicAdd(&dots[(size_t)(quad * 4 + r) * N + n0 + nrow],
                        ahh[r] + ahl[r] + alh[r]);

    float msq = (msqv.x + msqv.y) + (msqv.z + msqv.w);
    msq += __shfl_xor(msq, 16, 64);
    msq += __shfl_xor(msq, 32, 64);
    if (quad == 0) unsafeAtomicAdd(&mn2[n0 + nrow], msq);
}

// ---------------------------------------------------------------------------
// k_out partials, R2 FUSED local softmax (flash-style): each chunk c computes
// t = tan(cos*PI/2) for its 100 n (from L2-hot dots/mn2/kpart), takes local
// max mx[c][b] and partial sum Z[c][b], and accumulates the UNNORMALIZED
// exp-weighted sum  part[c][b][d4] = sum_n e^{t-mx} * mem[n][d4..+3]
// (scaled f16x4). meta[c][b] = (mx, Z) written by x-block 0. k_reduce does
// the cross-chunk rescale. Eliminates the 16-block k_softmax dispatch and
// its full-GPU pipeline bubble, and the w buffer.
// ---------------------------------------------------------------------------
__global__ __launch_bounds__(256, 4) void k_out_p(const float4* __restrict__ mem,
                                                  const float* __restrict__ dots,
                                                  const float* __restrict__ mn2,
                                                  const float* __restrict__ kpart,
                                                  uint2* __restrict__ part,
                                                  float2* __restrict__ meta) {
    const int tid = threadIdx.x;
    const int d4  = blockIdx.x * 256 + tid;
    const int c   = blockIdx.y;
    const int n0  = c * NPER;
    const int lane = tid & 63, wv = tid >> 6;

    __shared__ float wt[B * NPER];     // t, then p = e^{t-mx}
    __shared__ float sknp[16][16];
    __shared__ float skn[16];
    __shared__ float smn[NPER];
    __shared__ float mxs[16], Zs[16];

    // kn[b] = sqrt(sum_j kpart[j][b])  (196 deterministic partials, L2-hot)
    {
        float s = 0.f;
        for (int j = tid >> 4; j < KBLK; j += 16) s += kpart[j * 16 + (tid & 15)];
        sknp[tid >> 4][tid & 15] = s;
    }
    for (int i = tid; i < NPER; i += 256) smn[i] = fmaxf(sqrtf(mn2[n0 + i]), 1e-8f);
    __syncthreads();
    if (tid < 16) {
        float s = 0.f;
#pragma unroll
        for (int j = 0; j < 16; ++j) s += sknp[j][tid];
        skn[tid] = fmaxf(sqrtf(s), 1e-8f);
    }
    __syncthreads();

    // t = tan(cos * PI/2) for this chunk's 16 x 100 entries
    for (int i = tid; i < B * NPER; i += 256) {
        const int b = i / NPER, n = i % NPER;
        wt[i] = tanf(dots[(size_t)b * N + n0 + n] / (skn[b] * smn[n]) * PI2);
    }
    __syncthreads();

    // per-b local max + exp + partial sum; wave wv handles b = wv, wv+4, wv+8, wv+12
#pragma unroll
    for (int j = 0; j < 4; ++j) {
        const int b = wv + 4 * j;
        float v0 = wt[b * NPER + lane];
        float v1 = (lane + 64 < NPER) ? wt[b * NPER + lane + 64] : -1e30f;
        float mx = wave_max(fmaxf(v0, v1));
        float e0 = expf(v0 - mx);
        float e1 = (lane + 64 < NPER) ? expf(v1 - mx) : 0.f;
        wt[b * NPER + lane] = e0;
        if (lane + 64 < NPER) wt[b * NPER + lane + 64] = e1;
        float Z = wave_sum(e0 + e1);
        if (lane == 0) { mxs[b] = mx; Zs[b] = Z; }
    }
    __syncthreads();
    if (blockIdx.x == 0 && tid < 16) meta[c * 16 + tid] = make_float2(mxs[tid], Zs[tid]);
    if (d4 >= D4) return;

    const float4* mp = mem + (size_t)n0 * D4 + d4;
    float4 acc[B];
#pragma unroll
    for (int b = 0; b < B; ++b) acc[b] = make_float4(0.f, 0.f, 0.f, 0.f);

    float4 cur[4];
#pragma unroll
    for (int u = 0; u < 4; ++u) cur[u] = mp[(size_t)u * D4];

    for (int g = 0; g < NPER / 4; ++g) {     // 25 groups of 4
        const int gn = (g + 1 < NPER / 4) ? g + 1 : g;
        float4 nxt[4];
#pragma unroll
        for (int u = 0; u < 4; ++u) nxt[u] = mp[(size_t)(gn * 4 + u) * D4];
#pragma unroll
        for (int b = 0; b < B; ++b) {
            const float4 wv4 = *((const float4*)(wt + b * NPER) + g);
            float4 a = acc[b];
            a.x = fmaf(wv4.x, cur[0].x, a.x); a.y = fmaf(wv4.x, cur[0].y, a.y);
            a.z = fmaf(wv4.x, cur[0].z, a.z); a.w = fmaf(wv4.x, cur[0].w, a.w);
            a.x = fmaf(wv4.y, cur[1].x, a.x); a.y = fmaf(wv4.y, cur[1].y, a.y);
            a.z = fmaf(wv4.y, cur[1].z, a.z); a.w = fmaf(wv4.y, cur[1].w, a.w);
            a.x = fmaf(wv4.z, cur[2].x, a.x); a.y = fmaf(wv4.z, cur[2].y, a.y);
            a.z = fmaf(wv4.z, cur[2].z, a.z); a.w = fmaf(wv4.z, cur[2].w, a.w);
            a.x = fmaf(wv4.w, cur[3].x, a.x); a.y = fmaf(wv4.w, cur[3].y, a.y);
            a.z = fmaf(wv4.w, cur[3].z, a.z); a.w = fmaf(wv4.w, cur[3].w, a.w);
            acc[b] = a;
        }
#pragma unroll
        for (int u = 0; u < 4; ++u) cur[u] = nxt[u];
    }
#pragma unroll
    for (int b = 0; b < B; ++b) {
        hpk p0, p1;
        p0.h = __floats2half2_rn(acc[b].x * PSCALE, acc[b].y * PSCALE);
        p1.h = __floats2half2_rn(acc[b].z * PSCALE, acc[b].w * PSCALE);
        uint2 v; v.x = p0.u; v.y = p1.u;
        part[((size_t)c * B + b) * D4 + d4] = v;
    }
}

// Cross-chunk rescale + reduce: out = sum_c e^{mx_c-MX} acc_c / sum_c e^{mx_c-MX} Z_c
__global__ void k_reduce(const uint2* __restrict__ part, const float2* __restrict__ meta,
                         float4* __restrict__ out) {
    const int tid = threadIdx.x;
    __shared__ float2 smeta[NCHUNK * 16];
    __shared__ float scl[NCHUNK * 16];
    for (int j = tid; j < NCHUNK * 16; j += 256) smeta[j] = meta[j];
    __syncthreads();
    if (tid < 16) {
        float MX = -1e30f;
#pragma unroll
        for (int c = 0; c < NCHUNK; ++c) MX = fmaxf(MX, smeta[c * 16 + tid].x);
        float den = 0.f;
#pragma unroll
        for (int c = 0; c < NCHUNK; ++c)
            den += expf(smeta[c * 16 + tid].x - MX) * smeta[c * 16 + tid].y;
        const float inv = 1.f / den;
#pragma unroll
        for (int c = 0; c < NCHUNK; ++c)
            scl[c * 16 + tid] = expf(smeta[c * 16 + tid].x - MX) * inv;
    }
    __syncthreads();
    const int i = blockIdx.x * 256 + tid;   // < B*D4 = 100352
    const int b = i / D4;
    float sx = 0.f, sy = 0.f, sz = 0.f, sw = 0.f;
#pragma unroll
    for (int c = 0; c < NCHUNK; ++c) {
        uint2 v = part[(size_t)c * B * D4 + i];
        hpk a, b2; a.u = v.x; b2.u = v.y;
        float2 f0 = __half22float2(a.h), f1 = __half22float2(b2.h);
        const float sc = scl[c * 16 + b];
        sx = fmaf(sc, f0.x, sx); sy = fmaf(sc, f0.y, sy);
        sz = fmaf(sc, f1.x, sz); sw = fmaf(sc, f1.y, sw);
    }
    out[i] = make_float4(sx * PINV, sy * PINV, sz * PINV, sw * PINV);
}

// ---- fallback path (small workspace): normalized softmax + atomics to out ----
__global__ __launch_bounds__(256, 2) void k_softmax(const float* __restrict__ kpart,
                                                    const float* __restrict__ dots,
                                                    const float* __restrict__ mn2,
                                                    float* __restrict__ w) {
    const int b = blockIdx.x, tid = threadIdx.x;
    const int wv = tid >> 6, ln = tid & 63;
    __shared__ float t[N];
    __shared__ float redB[4], redC[4];

    float s = (tid < KBLK) ? kpart[tid * 16 + b] : 0.f;
    s = wave_sum(s);
    if (ln == 0) redB[wv] = s;
    __syncthreads();
    const float kn = fmaxf(sqrtf(redB[0] + redB[1] + redB[2] + redB[3]), 1e-8f);
    __syncthreads();

    float mx = -1e30f;
    for (int n = tid; n < N; n += 256) {
        float mn = fmaxf(sqrtf(mn2[n]), 1e-8f);
        float tv = tanf(dots[(size_t)b * N + n] / (kn * mn) * PI2);
        t[n] = tv;
        mx = fmaxf(mx, tv);
    }
    mx = wave_max(mx);
    if (ln == 0) redB[wv] = mx;
    __syncthreads();
    mx = fmaxf(fmaxf(redB[0], redB[1]), fmaxf(redB[2], redB[3]));

    float sum = 0.f;
    for (int n = tid; n < N; n += 256) {
        float e = expf(t[n] - mx);
        t[n] = e;
        sum += e;
    }
    sum = wave_sum(sum);
    if (ln == 0) redC[wv] = sum;
    __syncthreads();
    sum = redC[0] + redC[1] + redC[2] + redC[3];
    const float inv = 1.f / sum;
    for (int n = tid; n < N; n += 256) w[(size_t)b * N + n] = t[n] * inv;
}

__global__ __launch_bounds__(256, 2) void k_out_atomic(const float4* __restrict__ mem,
                                                       const float* __restrict__ w,
                                                       float* __restrict__ out) {
    const int tid = threadIdx.x;
    const int d4  = blockIdx.x * 256 + tid;
    const int n0  = blockIdx.y * NPER;
    __shared__ float wt[B * NPER];
    for (int i = tid; i < B * NPER; i += 256)
        wt[i] = w[(size_t)(i / NPER) * N + n0 + (i % NPER)];
    __syncthreads();
    if (d4 >= D4) return;
    const float4* mp = mem + (size_t)n0 * D4 + d4;
    float4 acc[B];
#pragma unroll
    for (int b = 0; b < B; ++b) acc[b] = make_float4(0.f, 0.f, 0.f, 0.f);
    for (int n = 0; n < NPER; n += 4) {
        float4 mv[4];
#pragma unroll
        for (int u = 0; u < 4; ++u) mv[u] = mp[(size_t)(n + u) * D4];
#pragma unroll
        for (int b = 0; b < B; ++b) {
            float4 a = acc[b];
#pragma unroll
            for (int u = 0; u < 4; ++u) {
                const float wv = wt[b * NPER + n + u];
                a.x = fmaf(wv, mv[u].x, a.x); a.y = fmaf(wv, mv[u].y, a.y);
                a.z = fmaf(wv, mv[u].z, a.z); a.w = fmaf(wv, mv[u].w, a.w);
            }
            acc[b] = a;
        }
    }
#pragma unroll
    for (int b = 0; b < B; ++b) {
        float* op = out + (size_t)b * D + (size_t)d4 * 4;
        unsafeAtomicAdd(op + 0, acc[b].x);
        unsafeAtomicAdd(op + 1, acc[b].y);
        unsafeAtomicAdd(op + 2, acc[b].z);
        unsafeAtomicAdd(op + 3, acc[b].w);
    }
}

extern "C" void kernel_launch(void* const* d_in, const int* in_sizes, int n_in,
                              void* d_out, int out_size, void* d_ws, size_t ws_size,
                              hipStream_t stream) {
    const float* key = (const float*)d_in[0];   // [16, 512, 7, 7]
    const float* mem = (const float*)d_in[1];   // [2000, 512, 7, 7]
    float* out = (float*)d_out;                 // [16, 512, 7, 7]

    // Workspace layout (floats), 16B-aligned sections.
    float* ws = (float*)d_ws;
    unsigned short* ksw = (unsigned short*)ws;          // 2*NT*64*8 ush = 401408 fl
    float* dots  = ws + 401408;                         // B*N  = 32000
    float* mn2   = dots + (size_t)B * N;                // N    =  2000  (contiguous after dots)
    float* kpart = mn2 + N;                             // KBLK*16 = 3136
    float* meta  = kpart + (size_t)KBLK * 16;           // NCHUNK*16 float2 = 640 fl
    float* w     = meta + (size_t)NCHUNK * 16 * 2;      // B*N = 32000 (fallback only)
    float* part  = w + (size_t)B * N;                   // NCHUNK*B*D4 uint2 = NCHUNK*B*D4*2 fl
    const size_t need_full =
        (size_t)(401408 + B * N + N + KBLK * 16 + NCHUNK * 32 + B * N
                 + (size_t)NCHUNK * B * D4 * 2) * 4;

    k_split<<<dim3(KBLK), 256, 0, stream>>>(key, ksw, dots, kpart);
    k_dots<<<dim3(N / 16, KC / 4), 256, 0, stream>>>(mem, ksw, dots, mn2);
    if (ws_size >= need_full) {
        k_out_p<<<dim3((D4 + 255) / 256, NCHUNK), 256, 0, stream>>>(
            (const float4*)mem, dots, mn2, kpart, (uint2*)part, (float2*)meta);
        k_reduce<<<dim3(B * D4 / 256), 256, 0, stream>>>((const uint2*)part,
                                                         (const float2*)meta, (float4*)out);
    } else {
        k_softmax<<<dim3(B), 256, 0, stream>>>(kpart, dots, mn2, w);
        hipMemsetAsync(d_out, 0, (size_t)B * D * sizeof(float), stream);
        k_out_atomic<<<dim3((D4 + 255) / 256, NCHUNK), 256, 0, stream>>>((const float4*)mem, w, out);
    }
}